// Round 7
// baseline (185.822 us; speedup 1.0000x reference)
//
#include <hip/hip_runtime.h>

#define NUM_LABELS 500
#define NB 8
#define NP (1024 * 1024)
#define CHUNKS 32                 // blocks per batch -> 256 blocks = 1/CU
#define PXB (NP / CHUNKS)         // 32768 px per block
#define TPB 128                   // 2 waves per block
#define NCOPY 32                  // histogram copies per wave region
#define REGION (NUM_LABELS * NCOPY)   // 16000 dwords per wave
#define DUMMY (2 * REGION)            // per-wave dummy slots (64 each)
#define LDS_DW (2 * REGION + 128)     // 32128 dwords = 128512 B

// Non-atomic LDS histogram, per-wave-private region, copy = lane&31.
//   Lane-pair (l, l^32) shares a copy -> dedup via __shfl_xor(32):
//   same label => lower lane accumulates both, upper lane writes dummy.
//   All 64 addresses of each ds_write are pairwise distinct => race-free
//   without atomics. bank = lane&31 -> exact 2-way = free.
// Packed u32 bin: [31:26] cnt  [25:12] sum round((v+32)*8)  [11:0] sum round(q*2)

__device__ __forceinline__ void lv_px(unsigned* __restrict__ h, int rbase, int dbase,
                                      int lane, int t, float a, float b, float c) {
    float v = a + b + c;
    float q = fmaf(a, a, fmaf(b, b, c * c));
    unsigned vf = (unsigned)fmaf(v, 8.f, 256.5f);   // round((v+32)*8)
    unsigned qf = (unsigned)fmaf(q, 2.f, 0.5f);     // round(q*2)
    unsigned pk = (1u << 26) | (vf << 12) | qf;

    int      tp  = __shfl_xor(t, 32, 64);
    unsigned pkp = (unsigned)__shfl_xor((int)pk, 32, 64);
    bool same  = (tp == t);
    bool lower = (lane < 32);
    unsigned pkw = (same && lower) ? pk + pkp : pk;
    bool toDummy = (t <= 0) || (same && !lower);
    int addr = toDummy ? (dbase + lane) : (rbase + t * NCOPY + (lane & 31));
    h[addr] += pkw;
}

__global__ __launch_bounds__(TPB, 1) void lv_bins(const float* __restrict__ x,
                                                  const int* __restrict__ tgt,
                                                  float* __restrict__ bins) {
    extern __shared__ unsigned h[];
    const int tid  = threadIdx.x;
    const int wv   = tid >> 6;
    const int lane = tid & 63;
    const int b    = blockIdx.y;

    for (int i = tid; i < LDS_DW / 4; i += TPB)
        ((uint4*)h)[i] = make_uint4(0u, 0u, 0u, 0u);
    __syncthreads();

    const int rbase = wv * REGION;
    const int dbase = DUMMY + wv * 64;

    const size_t base = (size_t)blockIdx.x * PXB + (size_t)wv * (PXB / 2);
    const int*   tg = tgt + (size_t)b * NP + base;
    const float* x0 = x + ((size_t)b * 3 + 0) * NP + base;
    const float* x1 = x + ((size_t)b * 3 + 1) * NP + base;
    const float* x2 = x + ((size_t)b * 3 + 2) * NP + base;

    const int laneOff = lane * 4;

    // ring of 4 slots, prefetch distance 4 => slot index it&3 is
    // compile-time under unroll-4 everywhere (no scratch demotion).
    int4 T[4]; float4 A[4], B[4], C[4];
#pragma unroll
    for (int s = 0; s < 4; ++s) {
        const int off = s * 256 + laneOff;
        T[s] = *(const int4*)(tg + off);
        A[s] = *(const float4*)(x0 + off);
        B[s] = *(const float4*)(x1 + off);
        C[s] = *(const float4*)(x2 + off);
    }

#pragma unroll 4
    for (int it = 0; it < 60; ++it) {          // 60 = 15*4, slots constant
        const int s = it & 3;
        lv_px(h, rbase, dbase, lane, T[s].x, A[s].x, B[s].x, C[s].x);
        lv_px(h, rbase, dbase, lane, T[s].y, A[s].y, B[s].y, C[s].y);
        lv_px(h, rbase, dbase, lane, T[s].z, A[s].z, B[s].z, C[s].z);
        lv_px(h, rbase, dbase, lane, T[s].w, A[s].w, B[s].w, C[s].w);

        const int off = (it + 4) * 256 + laneOff;
        T[s] = *(const int4*)(tg + off);
        A[s] = *(const float4*)(x0 + off);
        B[s] = *(const float4*)(x1 + off);
        C[s] = *(const float4*)(x2 + off);
    }
#pragma unroll
    for (int it = 60; it < 64; ++it) {
        const int s = it & 3;
        lv_px(h, rbase, dbase, lane, T[s].x, A[s].x, B[s].x, C[s].x);
        lv_px(h, rbase, dbase, lane, T[s].y, A[s].y, B[s].y, C[s].y);
        lv_px(h, rbase, dbase, lane, T[s].z, A[s].z, B[s].z, C[s].z);
        lv_px(h, rbase, dbase, lane, T[s].w, A[s].w, B[s].w, C[s].w);
    }

    __syncthreads();

    // Merge 64 slots (2 regions x 32 copies) per label; rotated copy index
    // keeps reads at 2-way/bank.
    float* g_s = bins;
    float* g_q = bins + NB * NUM_LABELS;
    float* g_c = bins + 2 * NB * NUM_LABELS;
    for (int t = tid; t < NUM_LABELS; t += TPB) {
        unsigned cs = 0, vs = 0, qs = 0;
#pragma unroll
        for (int r = 0; r < 2; ++r)
            for (int k = 0; k < NCOPY; ++k) {
                unsigned w = h[r * REGION + t * NCOPY + ((k + t) & 31)];
                cs += w >> 26;
                vs += (w >> 12) & 0x3FFFu;
                qs += w & 0xFFFu;
            }
        if (cs) {
            float cnt = (float)cs;
            float sv  = (float)vs * 0.125f - 32.f * cnt;
            float sq  = (float)qs * 0.5f;
            atomicAdd(&g_s[b * NUM_LABELS + t], sv);
            atomicAdd(&g_q[b * NUM_LABELS + t], sq);
            atomicAdd(&g_c[b * NUM_LABELS + t], cnt);
        }
    }
}

// Finalize: 8 waves, wave b reduces batch b over labels 1..499.
__global__ __launch_bounds__(512) void lv_final(const float* __restrict__ bins,
                                                float* __restrict__ out) {
    const int wave = threadIdx.x >> 6;
    const int lane = threadIdx.x & 63;

    const float* g_s = bins;
    const float* g_q = bins + NB * NUM_LABELS;
    const float* g_c = bins + 2 * NB * NUM_LABELS;

    float var_sum = 0.f;
    float uniq = 0.f;
    for (int l = 1 + lane; l < NUM_LABELS; l += 64) {
        float c = g_c[wave * NUM_LABELS + l];
        float s = g_s[wave * NUM_LABELS + l];
        float q = g_q[wave * NUM_LABELS + l];
        if (c > 0.f) uniq += 1.f;
        if (c > 1.f) {
            float N = 3.f * c;
            var_sum += (q - s * s / N) / (N - 1.f);
        }
    }
    for (int off = 32; off > 0; off >>= 1) {
        var_sum += __shfl_down(var_sum, off);
        uniq    += __shfl_down(uniq, off);
    }

    __shared__ float part[NB];
    if (lane == 0) part[wave] = var_sum / (uniq + 1e-8f);
    __syncthreads();

    if (threadIdx.x == 0) {
        float acc = 0.f;
        for (int i = 0; i < NB; ++i) acc += part[i];
        out[0] = acc * (1.f / NB);
    }
}

extern "C" void kernel_launch(void* const* d_in, const int* in_sizes, int n_in,
                              void* d_out, int out_size, void* d_ws, size_t ws_size,
                              hipStream_t stream) {
    const float* x   = (const float*)d_in[0];
    const int*   tgt = (const int*)d_in[1];
    float*       out = (float*)d_out;
    float*       bins = (float*)d_ws;  // 3 * 8 * 500 floats = 48 KB

    hipMemsetAsync(bins, 0, (size_t)3 * NB * NUM_LABELS * sizeof(float), stream);

    dim3 grid(CHUNKS, NB);   // 256 blocks, 2 waves each, 1 block/CU (125.5 KB LDS)
    lv_bins<<<grid, TPB, LDS_DW * sizeof(unsigned), stream>>>(x, tgt, bins);
    lv_final<<<1, 512, 0, stream>>>(bins, out);
}